// Round 8
// baseline (160.935 us; speedup 1.0000x reference)
//
#include <hip/hip_runtime.h>
#include <hip/hip_bf16.h>
#include <stdint.h>

typedef float  f32x4 __attribute__((ext_vector_type(4)));
typedef short  s16x8 __attribute__((ext_vector_type(8)));

#define NB    8
#define CIN   64
#define COUT  64
#define HH    128
#define WW    512
#define NTAP  17
#define PADW  152
#define XROW  816            // PADW + WW + PADW
#define BUFB  (XROW * 64)    // 52,224 B per buffer

// ---------------------------------------------------------------------------
// FAST PATH (MFMA)
// ---------------------------------------------------------------------------

// weights in A-fragment order: wf[(((t*2+p)*4+m)*64+l)*8+j] =
//   weff[t][ci = p*32 + 8*(l>>4)+j][co = 16m + (l&15)]  (bf16)
__global__ __launch_bounds__(256) void prep_wfrag(
        const float* __restrict__ W, const float* __restrict__ Bv,
        __hip_bfloat16* __restrict__ wf, float* __restrict__ bsum) {
    int idx = blockIdx.x * 256 + threadIdx.x;      // 69,632 total
    if (idx < NTAP * 2 * 4 * 64 * 8) {
        int j  = idx & 7;
        int l  = (idx >> 3) & 63;
        int m  = (idx >> 9) & 3;
        int pp = (idx >> 11) & 1;
        int t  = idx >> 12;
        int ci = pp * 32 + 8 * (l >> 4) + j;
        int co = 16 * m + (l & 15);
        float v;
        if (t == 0) {
            v = 0.f;
            #pragma unroll
            for (int i = 0; i < NB; ++i) v += W[((i * COUT + co) * CIN + ci) * 3 + 1];
        } else if (t <= 8) {
            v = W[(((t - 1) * COUT + co) * CIN + ci) * 3 + 0];
        } else {
            v = W[(((t - 9) * COUT + co) * CIN + ci) * 3 + 2];
        }
        wf[idx] = __float2bfloat16(v);
    }
    if (idx < COUT) {
        float s = 0.f;
        #pragma unroll
        for (int i = 0; i < NB; ++i) s += Bv[i * COUT + idx];
        bsum[idx] = s;
    }
}

// x -> bf16, PRE-SWIZZLED layout xt[b][h][p][w][slot]:
//   slot sc holds data chunk c = sc ^ ((w>>1)&3)   (involution)
// so that main's LINEAR global_load_lds produces LDS[row=PADW+w][slot] with
// chunk = slot ^ ((row>>1)&3)  — exactly what the swizzled ds_read expects
// (PADW=152 ≡ 0 mod 8 makes (row>>1)&3 == (w>>1)&3).
__global__ __launch_bounds__(256) void prep_xt(
        const float* __restrict__ x, __hip_bfloat16* __restrict__ xt) {
    __shared__ float tile[64][68];                 // [ci][w] padded (+4)
    int blk = blockIdx.x;                          // b*1024 + h*8 + wc
    int wc = blk & 7, h = (blk >> 3) & 127, b = blk >> 10;
    int w0 = wc * 64;
    int t = threadIdx.x;
    {
        int ci = t >> 2, q = t & 3;
        const float* src = x + (((size_t)b * CIN + ci) * HH + h) * WW + w0 + q * 16;
        float* dst = &tile[ci][q * 16];
        #pragma unroll
        for (int k = 0; k < 4; ++k)
            reinterpret_cast<float4*>(dst)[k] = reinterpret_cast<const float4*>(src)[k];
    }
    __syncthreads();
    int w = t & 63, sc = t >> 6;                   // sc = output slot 0..3
    int wg = w0 + w;
    int c = sc ^ ((wg >> 1) & 3);                  // data chunk stored at slot sc
    #pragma unroll
    for (int p = 0; p < 2; ++p) {
        int cibase = p * 32 + c * 8;
        union { __hip_bfloat16 hs[8]; int4 v; } pk;
        #pragma unroll
        for (int j = 0; j < 8; ++j) pk.hs[j] = __float2bfloat16(tile[cibase + j][w]);
        *reinterpret_cast<int4*>((char*)xt +
            ((((size_t)(b * HH + h) * 2 + p) * WW + wg) * 64 + sc * 16)) = pk.v;
    }
}

// Persistent pipelined main: grid 256 x 512 thr. Each block: 4 (b,h) rows =
// 8 stage-units (p-halves), double-buffered LDS, counted-wait pipeline with
// raw s_barrier (ONE barrier per unit; never __syncthreads -> prefetch loads
// survive across barriers). Full 64-co per block (max MFMA per staged byte —
// R7 lesson). Stage issued AFTER compute so af-loads' vmcnt waits (in-order
// retirement, m135) never force-drain the prefetch queue.
__global__ __launch_bounds__(512, 2) void hdc_mfma(
        const __hip_bfloat16* __restrict__ xt, const __hip_bfloat16* __restrict__ wf,
        const float* __restrict__ bsum, float* __restrict__ out) {
    extern __shared__ __align__(16) char smem[];   // 2 * BUFB = 104,448 B

    const int tid  = threadIdx.x;
    const int wv   = tid >> 6;                     // wave 0..7
    const int lane = tid & 63;
    const int l15  = lane & 15;
    const int lhi  = lane >> 4;
    const int bh0  = blockIdx.x * 4;               // first of 4 rows
    const int wlo  = wv * 64;                      // wave's 64-w slice

    f32x4 acc[4][4];
    #pragma unroll
    for (int m = 0; m < 4; ++m) {
        f32x4 bi = *reinterpret_cast<const f32x4*>(bsum + 16 * m + 4 * lhi);
        #pragma unroll
        for (int n = 0; n < 4; ++n) acc[m][n] = bi;
    }

    // zero halos once in BOTH buffers (staging only writes the body)
    {
        const int4 z{0, 0, 0, 0};
        #pragma unroll
        for (int bb = 0; bb < 2; ++bb) {
            int4* base = reinterpret_cast<int4*>(smem + bb * BUFB);
            for (int f = tid; f < 608; f += 512) {
                base[f] = z;                       // left halo  rows [0,152)
                base[2656 + f] = z;                // right halo rows [664,816)
            }
        }
    }

    static constexpr int OFFS[NTAP] = {0, -48, -76, -96, -111, -124, -135, -144, -152,
                                          48,  76,  96,  111,  124,  135,  144,  152};

    // stage unit u (row u>>1, p-half u&1) into buffer u&1: 4 DMA loads/thread
    auto STAGE = [&](int u) {
        const char* gsrc = (const char*)xt +
            ((size_t)(bh0 + (u >> 1)) * 65536) + (size_t)(u & 1) * 32768;
        char* dst = smem + (u & 1) * BUFB + PADW * 64;
        #pragma unroll
        for (int it = 0; it < 4; ++it) {
            __builtin_amdgcn_global_load_lds(
                (const __attribute__((address_space(1))) uint32_t*)
                    (gsrc + (it * 512 + tid) * 16),
                (__attribute__((address_space(3))) uint32_t*)
                    (dst + (it * 512 + wv * 64) * 16),
                16, 0, 0);
        }
    };

    STAGE(0);

    for (int u = 0; u < 8; ++u) {
        // wait own staged loads (+ halo ds_writes on u=0), then block barrier
        asm volatile("s_waitcnt vmcnt(0) lgkmcnt(0)" ::: "memory");
        __builtin_amdgcn_sched_barrier(0);
        __builtin_amdgcn_s_barrier();

        const char* rb    = smem + (u & 1) * BUFB;
        const char* wbase = (const char*)wf + (u & 1) * 4096 + lane * 16;
        #pragma unroll
        for (int t = 0; t < NTAP; ++t) {
            s16x8 af[4];
            #pragma unroll
            for (int m = 0; m < 4; ++m)
                af[m] = *reinterpret_cast<const s16x8*>(wbase + t * 8192 + m * 1024);

            const int ldsrow = PADW + wlo + l15 + OFFS[t];
            const int slot   = lhi ^ ((ldsrow >> 1) & 3);   // n-invariant
            const char* bbase = rb + ldsrow * 64 + slot * 16;
            s16x8 bfr[4];
            #pragma unroll
            for (int n = 0; n < 4; ++n)
                bfr[n] = *reinterpret_cast<const s16x8*>(bbase + n * 1024);

            #pragma unroll
            for (int m = 0; m < 4; ++m)
                #pragma unroll
                for (int n = 0; n < 4; ++n)
                    acc[m][n] = __builtin_amdgcn_mfma_f32_16x16x32_bf16(
                        af[m], bfr[n], acc[m][n], 0, 0, 0);
        }

        if (u < 7) STAGE(u + 1);                   // prefetch into other buffer

        if (u & 1) {
            // row finished: ReLU + store, then reinit acc with bias
            const int bh = bh0 + (u >> 1);
            const int b = bh >> 7, h = bh & 127;
            float* obase = out +
                (((size_t)b * COUT + 4 * lhi) * HH + h) * WW + wlo + l15;
            #pragma unroll
            for (int m = 0; m < 4; ++m)
                #pragma unroll
                for (int n = 0; n < 4; ++n)
                    #pragma unroll
                    for (int r = 0; r < 4; ++r) {
                        float v = acc[m][n][r];
                        obase[(size_t)(16 * m + r) * (HH * WW) + 16 * n] =
                            v > 0.f ? v : 0.f;
                    }
            #pragma unroll
            for (int m = 0; m < 4; ++m) {
                f32x4 bi = *reinterpret_cast<const f32x4*>(bsum + 16 * m + 4 * lhi);
                #pragma unroll
                for (int n = 0; n < 4; ++n) acc[m][n] = bi;
            }
        }
    }
}

// ---------------------------------------------------------------------------
// FALLBACK (round-1 fp32 kernel) if ws_size is too small for the bf16 copy
// ---------------------------------------------------------------------------
#define CI_STAGE 16

__global__ void prep_weff_fb(const float* __restrict__ W, const float* __restrict__ Bv,
                             float* __restrict__ weff, float* __restrict__ bsum) {
    int idx = blockIdx.x * 256 + threadIdx.x;
    if (idx < CIN * NTAP * COUT) {
        int co = idx & 63;
        int t  = (idx >> 6) % NTAP;
        int ci = idx / (NTAP * COUT);
        float v;
        if (t == 0) {
            v = 0.f;
            #pragma unroll
            for (int i = 0; i < NB; ++i) v += W[(((i * COUT + co) * CIN + ci) * 3) + 1];
        } else if (t <= 8) {
            v = W[((((t - 1) * COUT + co) * CIN + ci) * 3) + 0];
        } else {
            v = W[((((t - 9) * COUT + co) * CIN + ci) * 3) + 2];
        }
        weff[(ci * NTAP + t) * COUT + co] = v;
    }
    if (idx < COUT) {
        float s = 0.f;
        #pragma unroll
        for (int i = 0; i < NB; ++i) s += Bv[i * COUT + idx];
        bsum[idx] = s;
    }
}

__global__ __launch_bounds__(256, 2) void hdc_fb(
        const float* __restrict__ x, const float* __restrict__ weff,
        const float* __restrict__ bsum, float* __restrict__ out) {
    __shared__ float xsf[CI_STAGE][XROW];
    const int bh  = blockIdx.x;
    const int b   = bh >> 7;
    const int h   = bh & (HH - 1);
    const int tid = threadIdx.x;
    const int cg  = tid >> 5;
    const int wl  = tid & 31;
    constexpr int OFFS[NTAP] = {0, -48, -76, -96, -111, -124, -135, -144, -152,
                                    48,  76,  96,  111,  124,  135,  144,  152};
    float acc[8][16];
    #pragma unroll
    for (int j = 0; j < 8; ++j) {
        const float bj = bsum[cg * 8 + j];
        #pragma unroll
        for (int i = 0; i < 16; ++i) acc[j][i] = bj;
    }
    const float* xrowbase = x + ((size_t)(b * CIN) * HH + h) * WW;
    for (int s = 0; s < CIN / CI_STAGE; ++s) {
        __syncthreads();
        for (int f = tid; f < CI_STAGE * PADW; f += 256) {
            int r = f / PADW, c = f - r * PADW;
            xsf[r][c] = 0.f;
            xsf[r][PADW + WW + c] = 0.f;
        }
        #pragma unroll
        for (int j = 0; j < 8; ++j) {
            int flat = j * 256 + tid;
            int r = flat >> 7, c4 = flat & 127;
            const float4 v = *reinterpret_cast<const float4*>(
                xrowbase + (size_t)(s * CI_STAGE + r) * (HH * WW) + c4 * 4);
            *reinterpret_cast<float4*>(&xsf[r][PADW + c4 * 4]) = v;
        }
        __syncthreads();
        for (int r = 0; r < CI_STAGE; ++r) {
            const int ci = s * CI_STAGE + r;
            const float* wrow = weff + (size_t)(ci * NTAP) * COUT + cg * 8;
            const float* xr   = &xsf[r][PADW + wl];
            #pragma unroll
            for (int t = 0; t < NTAP; ++t) {
                const float4 w0 = *reinterpret_cast<const float4*>(wrow + t * COUT);
                const float4 w1 = *reinterpret_cast<const float4*>(wrow + t * COUT + 4);
                float xv[16];
                #pragma unroll
                for (int i = 0; i < 16; ++i) xv[i] = xr[OFFS[t] + 32 * i];
                const float wv[8] = {w0.x, w0.y, w0.z, w0.w, w1.x, w1.y, w1.z, w1.w};
                #pragma unroll
                for (int j = 0; j < 8; ++j)
                    #pragma unroll
                    for (int i = 0; i < 16; ++i)
                        acc[j][i] = fmaf(wv[j], xv[i], acc[j][i]);
            }
        }
    }
    float* outbase = out + (((size_t)b * COUT + cg * 8) * HH + h) * WW + wl;
    #pragma unroll
    for (int j = 0; j < 8; ++j)
        #pragma unroll
        for (int i = 0; i < 16; ++i) {
            float v = acc[j][i];
            outbase[(size_t)j * (HH * WW) + 32 * i] = v > 0.f ? v : 0.f;
        }
}

// ---------------------------------------------------------------------------

extern "C" void kernel_launch(void* const* d_in, const int* in_sizes, int n_in,
                              void* d_out, int out_size, void* d_ws, size_t ws_size,
                              hipStream_t stream) {
    const float* x  = (const float*)d_in[0];
    const float* W  = (const float*)d_in[1];
    const float* Bv = (const float*)d_in[2];
    float* out = (float*)d_out;

    const size_t XT_OFF = (size_t)1 << 20;
    const size_t need = XT_OFF + (size_t)8 * HH * 2 * WW * 64;   // 1MB + 67,108,864

    if (ws_size >= need) {
        __hip_bfloat16* wf = (__hip_bfloat16*)d_ws;               // 139,264 B
        float* bsum = (float*)((char*)d_ws + 139264);             // 256 B
        __hip_bfloat16* xt = (__hip_bfloat16*)((char*)d_ws + XT_OFF);
        prep_wfrag<<<272, 256, 0, stream>>>(W, Bv, wf, bsum);
        prep_xt<<<8192, 256, 0, stream>>>(x, xt);
        (void)hipFuncSetAttribute((const void*)hdc_mfma,
            hipFuncAttributeMaxDynamicSharedMemorySize, 2 * BUFB);
        hdc_mfma<<<256, 512, 2 * BUFB, stream>>>(xt, wf, bsum, out);
    } else {
        float* weff = (float*)d_ws;
        float* bsum = weff + (size_t)CIN * NTAP * COUT;
        prep_weff_fb<<<(CIN * NTAP * COUT + 255) / 256, 256, 0, stream>>>(W, Bv, weff, bsum);
        hdc_fb<<<NB * HH, 256, 0, stream>>>(x, weff, bsum, out);
    }
}

// Round 9
// 125.808 us; speedup vs baseline: 1.2792x; 1.2792x over previous
//
#include <hip/hip_runtime.h>
#include <hip/hip_bf16.h>
#include <stdint.h>

typedef float  f32x4 __attribute__((ext_vector_type(4)));
typedef short  s16x8 __attribute__((ext_vector_type(8)));

#define NB    8
#define CIN   64
#define COUT  64
#define HH    128
#define WW    512
#define NTAP  17
#define PADW  152
#define XROW  816            // PADW + WW + PADW
#define BUFB  (XROW * 64)    // 52,224 B per buffer

// ---------------------------------------------------------------------------
// FAST PATH (MFMA)
// ---------------------------------------------------------------------------

// weights in A-fragment order: byte off = (2t+p)*4096 + m*1024 + lane*16
__global__ __launch_bounds__(256) void prep_wfrag(
        const float* __restrict__ W, const float* __restrict__ Bv,
        __hip_bfloat16* __restrict__ wf, float* __restrict__ bsum) {
    int idx = blockIdx.x * 256 + threadIdx.x;      // 69,632 total
    if (idx < NTAP * 2 * 4 * 64 * 8) {
        int j  = idx & 7;
        int l  = (idx >> 3) & 63;
        int m  = (idx >> 9) & 3;
        int pp = (idx >> 11) & 1;
        int t  = idx >> 12;
        int ci = pp * 32 + 8 * (l >> 4) + j;
        int co = 16 * m + (l & 15);
        float v;
        if (t == 0) {
            v = 0.f;
            #pragma unroll
            for (int i = 0; i < NB; ++i) v += W[((i * COUT + co) * CIN + ci) * 3 + 1];
        } else if (t <= 8) {
            v = W[(((t - 1) * COUT + co) * CIN + ci) * 3 + 0];
        } else {
            v = W[(((t - 9) * COUT + co) * CIN + ci) * 3 + 2];
        }
        wf[idx] = __float2bfloat16(v);
    }
    if (idx < COUT) {
        float s = 0.f;
        #pragma unroll
        for (int i = 0; i < NB; ++i) s += Bv[i * COUT + idx];
        bsum[idx] = s;
    }
}

// x -> bf16, PRE-SWIZZLED layout xt[b][h][p][w][slot]:
//   slot sc holds data chunk c = sc ^ ((w>>1)&3)   (involution)
__global__ __launch_bounds__(256) void prep_xt(
        const float* __restrict__ x, __hip_bfloat16* __restrict__ xt) {
    __shared__ float tile[64][68];                 // [ci][w] padded (+4)
    int blk = blockIdx.x;                          // b*1024 + h*8 + wc
    int wc = blk & 7, h = (blk >> 3) & 127, b = blk >> 10;
    int w0 = wc * 64;
    int t = threadIdx.x;
    {
        int ci = t >> 2, q = t & 3;
        const float* src = x + (((size_t)b * CIN + ci) * HH + h) * WW + w0 + q * 16;
        float* dst = &tile[ci][q * 16];
        #pragma unroll
        for (int k = 0; k < 4; ++k)
            reinterpret_cast<float4*>(dst)[k] = reinterpret_cast<const float4*>(src)[k];
    }
    __syncthreads();
    int w = t & 63, sc = t >> 6;                   // sc = output slot 0..3
    int wg = w0 + w;
    int c = sc ^ ((wg >> 1) & 3);                  // data chunk stored at slot sc
    #pragma unroll
    for (int p = 0; p < 2; ++p) {
        int cibase = p * 32 + c * 8;
        union { __hip_bfloat16 hs[8]; int4 v; } pk;
        #pragma unroll
        for (int j = 0; j < 8; ++j) pk.hs[j] = __float2bfloat16(tile[cibase + j][w]);
        *reinterpret_cast<int4*>((char*)xt +
            ((((size_t)(b * HH + h) * 2 + p) * WW + wg) * 64 + sc * 16)) = pk.v;
    }
}

static constexpr int OFFS[NTAP] = {0, -48, -76, -96, -111, -124, -135, -144, -152,
                                      48,  76,  96,  111,  124,  135,  144,  152};

#define LOADAF(AF, T0, CNT)                                                    \
    _Pragma("unroll")                                                          \
    for (int i = 0; i < (CNT); ++i)                                            \
        _Pragma("unroll")                                                      \
        for (int m = 0; m < 4; ++m)                                            \
            AF[i][m] = *reinterpret_cast<const s16x8*>(                        \
                wbase + ((T0) + i) * 8192 + m * 1024);

#define COMPTAPS(AF, T0, CNT)                                                  \
    _Pragma("unroll")                                                          \
    for (int i = 0; i < (CNT); ++i) {                                          \
        const int t      = (T0) + i;                                           \
        const int ldsrow = rowb + OFFS[t];                                     \
        const int slot   = lhi ^ ((ldsrow >> 1) & 3);                          \
        const char* bbase = rb + ldsrow * 64 + slot * 16;                      \
        s16x8 bfr[4];                                                          \
        _Pragma("unroll")                                                      \
        for (int n = 0; n < 4; ++n)                                            \
            bfr[n] = *reinterpret_cast<const s16x8*>(bbase + n * 1024);        \
        _Pragma("unroll")                                                      \
        for (int m = 0; m < 4; ++m)                                            \
            _Pragma("unroll")                                                  \
            for (int n = 0; n < 4; ++n)                                        \
                acc[m][n] = __builtin_amdgcn_mfma_f32_16x16x32_bf16(           \
                    AF[i][m], bfr[n], acc[m][n], 0, 0, 0);                     \
    }

// Persistent pipelined main: 256 blocks x 512 thr (8 waves x 64-w, all 4 m).
// Per unit: {vmcnt(0); barrier; load af batch0 (regs); STAGE(u+1); compute
// 3 tap-batches, af preloaded -> compute is vmem-free so the prefetch stays
// in flight through the whole compute (in-order vmcnt, m135)}.
__global__ __launch_bounds__(512, 2) void hdc_mfma(
        const __hip_bfloat16* __restrict__ xt, const __hip_bfloat16* __restrict__ wf,
        const float* __restrict__ bsum, float* __restrict__ out) {
    extern __shared__ __align__(16) char smem[];   // 2 * BUFB = 104,448 B

    const int tid  = threadIdx.x;
    const int wv   = tid >> 6;                     // wave 0..7
    const int lane = tid & 63;
    const int l15  = lane & 15;
    const int lhi  = lane >> 4;
    const int bh0  = blockIdx.x * 4;               // first of 4 rows
    const int wlo  = wv * 64;                      // wave's 64-w slice
    const int rowb = PADW + wlo + l15;

    f32x4 acc[4][4];
    #pragma unroll
    for (int m = 0; m < 4; ++m) {
        f32x4 bi = *reinterpret_cast<const f32x4*>(bsum + 16 * m + 4 * lhi);
        #pragma unroll
        for (int n = 0; n < 4; ++n) acc[m][n] = bi;
    }

    // zero halos once in BOTH buffers (staging only writes the body)
    {
        const int4 z{0, 0, 0, 0};
        #pragma unroll
        for (int bb = 0; bb < 2; ++bb) {
            int4* base = reinterpret_cast<int4*>(smem + bb * BUFB);
            for (int f = tid; f < 608; f += 512) {
                base[f] = z;                       // left halo  rows [0,152)
                base[2656 + f] = z;                // right halo rows [664,816)
            }
        }
    }
    __syncthreads();

    auto STAGE = [&](int u) {
        const char* gsrc = (const char*)xt +
            ((size_t)(bh0 + (u >> 1)) * 65536) + (size_t)(u & 1) * 32768;
        char* dst = smem + (u & 1) * BUFB + PADW * 64;
        #pragma unroll
        for (int it = 0; it < 4; ++it) {
            __builtin_amdgcn_global_load_lds(
                (const __attribute__((address_space(1))) uint32_t*)
                    (gsrc + (it * 512 + tid) * 16),
                (__attribute__((address_space(3))) uint32_t*)
                    (dst + (it * 512 + wv * 64) * 16),
                16, 0, 0);
        }
    };

    STAGE(0);

    for (int u = 0; u < 8; ++u) {
        // stage(u) landed; one barrier per unit
        asm volatile("s_waitcnt vmcnt(0) lgkmcnt(0)" ::: "memory");
        __builtin_amdgcn_sched_barrier(0);
        __builtin_amdgcn_s_barrier();

        const char* wbase = (const char*)wf + (u & 1) * 4096 + lane * 16;
        const char* rb    = smem + (u & 1) * BUFB;

        s16x8 af0[6][4], af1[6][4], af2[5][4];

        LOADAF(af0, 0, 6)                          // oldest vmem: batch0
        __builtin_amdgcn_sched_barrier(0);
        if (u < 7) STAGE(u + 1);                   // newest: prefetch (stays in flight)
        __builtin_amdgcn_sched_barrier(0);

        COMPTAPS(af0, 0, 6)
        __builtin_amdgcn_sched_barrier(0);
        LOADAF(af1, 6, 6)
        __builtin_amdgcn_sched_barrier(0);
        COMPTAPS(af1, 6, 6)
        __builtin_amdgcn_sched_barrier(0);
        LOADAF(af2, 12, 5)
        __builtin_amdgcn_sched_barrier(0);
        COMPTAPS(af2, 12, 5)

        if (u & 1) {
            // row finished: ReLU + store, then reinit acc with bias
            const int bh = bh0 + (u >> 1);
            const int b = bh >> 7, h = bh & 127;
            float* obase = out +
                (((size_t)b * COUT + 4 * lhi) * HH + h) * WW + wlo + l15;
            #pragma unroll
            for (int m = 0; m < 4; ++m)
                #pragma unroll
                for (int n = 0; n < 4; ++n)
                    #pragma unroll
                    for (int r = 0; r < 4; ++r) {
                        float v = acc[m][n][r];
                        obase[(size_t)(16 * m + r) * (HH * WW) + 16 * n] =
                            v > 0.f ? v : 0.f;
                    }
            #pragma unroll
            for (int m = 0; m < 4; ++m) {
                f32x4 bi = *reinterpret_cast<const f32x4*>(bsum + 16 * m + 4 * lhi);
                #pragma unroll
                for (int n = 0; n < 4; ++n) acc[m][n] = bi;
            }
        }
    }
}

// ---------------------------------------------------------------------------
// FALLBACK (round-1 fp32 kernel) if ws_size is too small for the bf16 copy
// ---------------------------------------------------------------------------
#define CI_STAGE 16

__global__ void prep_weff_fb(const float* __restrict__ W, const float* __restrict__ Bv,
                             float* __restrict__ weff, float* __restrict__ bsum) {
    int idx = blockIdx.x * 256 + threadIdx.x;
    if (idx < CIN * NTAP * COUT) {
        int co = idx & 63;
        int t  = (idx >> 6) % NTAP;
        int ci = idx / (NTAP * COUT);
        float v;
        if (t == 0) {
            v = 0.f;
            #pragma unroll
            for (int i = 0; i < NB; ++i) v += W[(((i * COUT + co) * CIN + ci) * 3) + 1];
        } else if (t <= 8) {
            v = W[((((t - 1) * COUT + co) * CIN + ci) * 3) + 0];
        } else {
            v = W[((((t - 9) * COUT + co) * CIN + ci) * 3) + 2];
        }
        weff[(ci * NTAP + t) * COUT + co] = v;
    }
    if (idx < COUT) {
        float s = 0.f;
        #pragma unroll
        for (int i = 0; i < NB; ++i) s += Bv[i * COUT + idx];
        bsum[idx] = s;
    }
}

__global__ __launch_bounds__(256, 2) void hdc_fb(
        const float* __restrict__ x, const float* __restrict__ weff,
        const float* __restrict__ bsum, float* __restrict__ out) {
    __shared__ float xsf[CI_STAGE][XROW];
    const int bh  = blockIdx.x;
    const int b   = bh >> 7;
    const int h   = bh & (HH - 1);
    const int tid = threadIdx.x;
    const int cg  = tid >> 5;
    const int wl  = tid & 31;
    float acc[8][16];
    #pragma unroll
    for (int j = 0; j < 8; ++j) {
        const float bj = bsum[cg * 8 + j];
        #pragma unroll
        for (int i = 0; i < 16; ++i) acc[j][i] = bj;
    }
    const float* xrowbase = x + ((size_t)(b * CIN) * HH + h) * WW;
    for (int s = 0; s < CIN / CI_STAGE; ++s) {
        __syncthreads();
        for (int f = tid; f < CI_STAGE * PADW; f += 256) {
            int r = f / PADW, c = f - r * PADW;
            xsf[r][c] = 0.f;
            xsf[r][PADW + WW + c] = 0.f;
        }
        #pragma unroll
        for (int j = 0; j < 8; ++j) {
            int flat = j * 256 + tid;
            int r = flat >> 7, c4 = flat & 127;
            const float4 v = *reinterpret_cast<const float4*>(
                xrowbase + (size_t)(s * CI_STAGE + r) * (HH * WW) + c4 * 4);
            *reinterpret_cast<float4*>(&xsf[r][PADW + c4 * 4]) = v;
        }
        __syncthreads();
        for (int r = 0; r < CI_STAGE; ++r) {
            const int ci = s * CI_STAGE + r;
            const float* wrow = weff + (size_t)(ci * NTAP) * COUT + cg * 8;
            const float* xr   = &xsf[r][PADW + wl];
            #pragma unroll
            for (int t = 0; t < NTAP; ++t) {
                const float4 w0 = *reinterpret_cast<const float4*>(wrow + t * COUT);
                const float4 w1 = *reinterpret_cast<const float4*>(wrow + t * COUT + 4);
                float xv[16];
                #pragma unroll
                for (int i = 0; i < 16; ++i) xv[i] = xr[OFFS[t] + 32 * i];
                const float wv[8] = {w0.x, w0.y, w0.z, w0.w, w1.x, w1.y, w1.z, w1.w};
                #pragma unroll
                for (int j = 0; j < 8; ++j)
                    #pragma unroll
                    for (int i = 0; i < 16; ++i)
                        acc[j][i] = fmaf(wv[j], xv[i], acc[j][i]);
            }
        }
    }
    float* outbase = out + (((size_t)b * COUT + cg * 8) * HH + h) * WW + wl;
    #pragma unroll
    for (int j = 0; j < 8; ++j)
        #pragma unroll
        for (int i = 0; i < 16; ++i) {
            float v = acc[j][i];
            outbase[(size_t)j * (HH * WW) + 32 * i] = v > 0.f ? v : 0.f;
        }
}

// ---------------------------------------------------------------------------

extern "C" void kernel_launch(void* const* d_in, const int* in_sizes, int n_in,
                              void* d_out, int out_size, void* d_ws, size_t ws_size,
                              hipStream_t stream) {
    const float* x  = (const float*)d_in[0];
    const float* W  = (const float*)d_in[1];
    const float* Bv = (const float*)d_in[2];
    float* out = (float*)d_out;

    const size_t XT_OFF = (size_t)1 << 20;
    const size_t need = XT_OFF + (size_t)8 * HH * 2 * WW * 64;   // 1MB + 67,108,864

    if (ws_size >= need) {
        __hip_bfloat16* wf = (__hip_bfloat16*)d_ws;               // 139,264 B
        float* bsum = (float*)((char*)d_ws + 139264);             // 256 B
        __hip_bfloat16* xt = (__hip_bfloat16*)((char*)d_ws + XT_OFF);
        prep_wfrag<<<272, 256, 0, stream>>>(W, Bv, wf, bsum);
        prep_xt<<<8192, 256, 0, stream>>>(x, xt);
        (void)hipFuncSetAttribute((const void*)hdc_mfma,
            hipFuncAttributeMaxDynamicSharedMemorySize, 2 * BUFB);
        hdc_mfma<<<256, 512, 2 * BUFB, stream>>>(xt, wf, bsum, out);
    } else {
        float* weff = (float*)d_ws;
        float* bsum = weff + (size_t)CIN * NTAP * COUT;
        prep_weff_fb<<<(CIN * NTAP * COUT + 255) / 256, 256, 0, stream>>>(W, Bv, weff, bsum);
        hdc_fb<<<NB * HH, 256, 0, stream>>>(x, weff, bsum, out);
    }
}

// Round 10
// 84.876 us; speedup vs baseline: 1.8961x; 1.4823x over previous
//
#include <hip/hip_runtime.h>
#include <hip/hip_bf16.h>
#include <stdint.h>

typedef float  f32x4 __attribute__((ext_vector_type(4)));
typedef short  s16x8 __attribute__((ext_vector_type(8)));

#define NB    8
#define CIN   64
#define COUT  64
#define HH    128
#define WW    512
#define NTAP  17
#define PADW  152
#define XROW  816            // PADW + WW + PADW
#define BUFB  (XROW * 64)    // 52,224 B per buffer
#define HW    (HH * WW)

// ---------------------------------------------------------------------------
// weights in A-fragment order: byte off = (2t+p)*4096 + m*1024 + lane*16
__global__ __launch_bounds__(256) void prep_wfrag(
        const float* __restrict__ W, const float* __restrict__ Bv,
        __hip_bfloat16* __restrict__ wf, float* __restrict__ bsum) {
    int idx = blockIdx.x * 256 + threadIdx.x;      // 69,632 total
    if (idx < NTAP * 2 * 4 * 64 * 8) {
        int j  = idx & 7;
        int l  = (idx >> 3) & 63;
        int m  = (idx >> 9) & 3;
        int pp = (idx >> 11) & 1;
        int t  = idx >> 12;
        int ci = pp * 32 + 8 * (l >> 4) + j;
        int co = 16 * m + (l & 15);
        float v;
        if (t == 0) {
            v = 0.f;
            #pragma unroll
            for (int i = 0; i < NB; ++i) v += W[((i * COUT + co) * CIN + ci) * 3 + 1];
        } else if (t <= 8) {
            v = W[(((t - 1) * COUT + co) * CIN + ci) * 3 + 0];
        } else {
            v = W[(((t - 9) * COUT + co) * CIN + ci) * 3 + 2];
        }
        wf[idx] = __float2bfloat16(v);
    }
    if (idx < COUT) {
        float s = 0.f;
        #pragma unroll
        for (int i = 0; i < NB; ++i) s += Bv[i * COUT + idx];
        bsum[idx] = s;
    }
}

static constexpr int OFFS[NTAP] = {0, -48, -76, -96, -111, -124, -135, -144, -152,
                                      48,  76,  96,  111,  124,  135,  144,  152};

#define SB __builtin_amdgcn_sched_barrier(0)

#define LOADAF(AF, T0, CNT)                                                    \
    _Pragma("unroll")                                                          \
    for (int i = 0; i < (CNT); ++i)                                            \
        _Pragma("unroll")                                                      \
        for (int m = 0; m < 4; ++m)                                            \
            AF[i][m] = *reinterpret_cast<const s16x8*>(                        \
                wbase + ((T0) + i) * 8192 + m * 1024);

#define COMPTAPS(AF, T0, CNT)                                                  \
    _Pragma("unroll")                                                          \
    for (int i = 0; i < (CNT); ++i) {                                          \
        const int t      = (T0) + i;                                           \
        const int ldsrow = rowb + OFFS[t];                                     \
        const int slot   = lhi ^ ((ldsrow >> 1) & 3);                          \
        const char* bbase = rb + ldsrow * 64 + slot * 16;                      \
        s16x8 bfr[8];                                                          \
        _Pragma("unroll")                                                      \
        for (int n = 0; n < 8; ++n)                                            \
            bfr[n] = *reinterpret_cast<const s16x8*>(bbase + n * 1024);        \
        _Pragma("unroll")                                                      \
        for (int m = 0; m < 4; ++m)                                            \
            _Pragma("unroll")                                                  \
            for (int n = 0; n < 8; ++n)                                        \
                acc[m][n] = __builtin_amdgcn_mfma_f32_16x16x32_bf16(           \
                    AF[i][m], bfr[n], acc[m][n], 0, 0, 0);                     \
    }

// Fused persistent main: 256 blocks x 256 thr (4 waves, n=8 -> halves weight
// L2 traffic vs 8-wave n=4). Per unit (p-half of a (b,h) row): af batches +
// MFMA on buf[u&1]; stage-loads for u+1 issued as the NEWEST vmem (after af2)
// so af waits never drain them (in-order vmcnt retirement, m135); they land
// under C2, then vmcnt(0) + cvt->bf16 + swizzled ds_write into buf[(u+1)&1]
// (byte-identical LDS contents to the verified R3/R5 layout). One raw
// s_barrier per unit. prep_xt eliminated: x read once as fp32 (134MB),
// out written once (134MB) -> whole-kernel memory floor ~43us.
__global__ __launch_bounds__(256, 1) void hdc_mfma(
        const float* __restrict__ x, const __hip_bfloat16* __restrict__ wf,
        const float* __restrict__ bsum, float* __restrict__ out) {
    extern __shared__ __align__(16) char smem[];   // 2 * BUFB = 104,448 B

    const int tid  = threadIdx.x;
    const int wv   = tid >> 6;                     // wave 0..3
    const int lane = tid & 63;
    const int l15  = lane & 15;
    const int lhi  = lane >> 4;
    const int c    = tid >> 6;                     // staging chunk 0..3 (= wv)
    const int wl   = tid & 63;                     // staging w-lane
    const int bh0  = blockIdx.x * 4;               // 4 rows per block
    const int wlo  = wv * 128;                     // wave's 128-w slice (n=8)
    const int rowb = PADW + wlo + l15;

    f32x4 acc[4][8];
    #pragma unroll
    for (int m = 0; m < 4; ++m) {
        f32x4 bi = *reinterpret_cast<const f32x4*>(bsum + 16 * m + 4 * lhi);
        #pragma unroll
        for (int n = 0; n < 8; ++n) acc[m][n] = bi;
    }

    // zero halos once in BOTH buffers (staging writes body rows only)
    {
        const int4 z{0, 0, 0, 0};
        #pragma unroll
        for (int bb = 0; bb < 2; ++bb) {
            int4* base = reinterpret_cast<int4*>(smem + bb * BUFB);
            for (int f = tid; f < 608; f += 256) {
                base[f] = z;                       // left halo  rows [0,152)
                base[2656 + f] = z;                // right halo rows [664,816)
            }
        }
    }

    float4 xv0[8], xv1[8];                         // staged fp32: 8ci x (4w,4w+256)

    // issue coalesced fp32 loads for unit u (16 x dwordx4, lanes consecutive w)
    auto SLOAD = [&](int u) {
        const int r = bh0 + (u >> 1);
        const int b = r >> 7, h = r & 127;
        const float* src = x +
            (((size_t)(b * CIN + (u & 1) * 32 + c * 8) * HH + h) * WW) + wl * 4;
        #pragma unroll
        for (int j = 0; j < 8; ++j) {
            xv0[j] = *reinterpret_cast<const float4*>(src + j * HW);
            xv1[j] = *reinterpret_cast<const float4*>(src + j * HW + 256);
        }
    };
    // cvt + swizzled LDS write into buf[u&1]
    auto SWRITE = [&](int u) {
        char* dst = smem + (u & 1) * BUFB;
        #pragma unroll
        for (int q = 0; q < 2; ++q) {
            #pragma unroll
            for (int k = 0; k < 4; ++k) {
                const int row  = PADW + wl * 4 + k + q * 256;
                const int slot = c ^ ((row >> 1) & 3);
                union { __hip_bfloat16 hs[8]; int4 iv; } pk;
                #pragma unroll
                for (int j = 0; j < 8; ++j) {
                    const float4& v = q ? xv1[j] : xv0[j];
                    pk.hs[j] = __float2bfloat16(((const float*)&v)[k]);
                }
                *reinterpret_cast<int4*>(dst + row * 64 + slot * 16) = pk.iv;
            }
        }
    };

    // prologue: fill buf0
    SLOAD(0);
    asm volatile("s_waitcnt vmcnt(0)" ::: "memory");
    SB;
    SWRITE(0);
    __syncthreads();

    for (int u = 0; u < 8; ++u) {
        const char* wbase = (const char*)wf + (u & 1) * 4096 + lane * 16;
        const char* rb    = smem + (u & 1) * BUFB;

        s16x8 af0[6][4], af1[6][4], af2[5][4];

        LOADAF(af0, 0, 6)  SB;
        COMPTAPS(af0, 0, 6) SB;
        LOADAF(af1, 6, 6)  SB;
        COMPTAPS(af1, 6, 6) SB;
        LOADAF(af2, 12, 5) SB;
        if (u < 7) SLOAD(u + 1);                   // newest vmem: stays in flight
        SB;
        COMPTAPS(af2, 12, 5) SB;

        if (u < 7) {
            asm volatile("s_waitcnt vmcnt(0)" ::: "memory");   // stage landed
            SB;
            SWRITE(u + 1);                         // into buf[(u+1)&1]
        }

        if (u & 1) {
            // row finished: ReLU + store, reinit acc with bias
            const int r = bh0 + (u >> 1);
            const int b = r >> 7, h = r & 127;
            float* obase = out +
                (((size_t)b * COUT + 4 * lhi) * HH + h) * WW + wlo + l15;
            #pragma unroll
            for (int m = 0; m < 4; ++m)
                #pragma unroll
                for (int n = 0; n < 8; ++n)
                    #pragma unroll
                    for (int rr = 0; rr < 4; ++rr) {
                        float v = acc[m][n][rr];
                        obase[(size_t)(16 * m + rr) * HW + 16 * n] =
                            v > 0.f ? v : 0.f;
                    }
            #pragma unroll
            for (int m = 0; m < 4; ++m) {
                f32x4 bi = *reinterpret_cast<const f32x4*>(bsum + 16 * m + 4 * lhi);
                #pragma unroll
                for (int n = 0; n < 8; ++n) acc[m][n] = bi;
            }
        }

        asm volatile("s_waitcnt lgkmcnt(0)" ::: "memory");     // ds_writes done
        SB;
        __builtin_amdgcn_s_barrier();              // buf[(u+1)&1] ready for all
    }
}

// ---------------------------------------------------------------------------
// FALLBACK (round-1 fp32 kernel) if ws_size is too small for weight scratch
// ---------------------------------------------------------------------------
#define CI_STAGE 16

__global__ void prep_weff_fb(const float* __restrict__ W, const float* __restrict__ Bv,
                             float* __restrict__ weff, float* __restrict__ bsum) {
    int idx = blockIdx.x * 256 + threadIdx.x;
    if (idx < CIN * NTAP * COUT) {
        int co = idx & 63;
        int t  = (idx >> 6) % NTAP;
        int ci = idx / (NTAP * COUT);
        float v;
        if (t == 0) {
            v = 0.f;
            #pragma unroll
            for (int i = 0; i < NB; ++i) v += W[(((i * COUT + co) * CIN + ci) * 3) + 1];
        } else if (t <= 8) {
            v = W[((((t - 1) * COUT + co) * CIN + ci) * 3) + 0];
        } else {
            v = W[((((t - 9) * COUT + co) * CIN + ci) * 3) + 2];
        }
        weff[(ci * NTAP + t) * COUT + co] = v;
    }
    if (idx < COUT) {
        float s = 0.f;
        #pragma unroll
        for (int i = 0; i < NB; ++i) s += Bv[i * COUT + idx];
        bsum[idx] = s;
    }
}

__global__ __launch_bounds__(256, 2) void hdc_fb(
        const float* __restrict__ x, const float* __restrict__ weff,
        const float* __restrict__ bsum, float* __restrict__ out) {
    __shared__ float xsf[CI_STAGE][XROW];
    const int bh  = blockIdx.x;
    const int b   = bh >> 7;
    const int h   = bh & (HH - 1);
    const int tid = threadIdx.x;
    const int cg  = tid >> 5;
    const int wl  = tid & 31;
    float acc[8][16];
    #pragma unroll
    for (int j = 0; j < 8; ++j) {
        const float bj = bsum[cg * 8 + j];
        #pragma unroll
        for (int i = 0; i < 16; ++i) acc[j][i] = bj;
    }
    const float* xrowbase = x + ((size_t)(b * CIN) * HH + h) * WW;
    for (int s = 0; s < CIN / CI_STAGE; ++s) {
        __syncthreads();
        for (int f = tid; f < CI_STAGE * PADW; f += 256) {
            int r = f / PADW, cc = f - r * PADW;
            xsf[r][cc] = 0.f;
            xsf[r][PADW + WW + cc] = 0.f;
        }
        #pragma unroll
        for (int j = 0; j < 8; ++j) {
            int flat = j * 256 + tid;
            int r = flat >> 7, c4 = flat & 127;
            const float4 v = *reinterpret_cast<const float4*>(
                xrowbase + (size_t)(s * CI_STAGE + r) * HW + c4 * 4);
            *reinterpret_cast<float4*>(&xsf[r][PADW + c4 * 4]) = v;
        }
        __syncthreads();
        for (int r = 0; r < CI_STAGE; ++r) {
            const int ci = s * CI_STAGE + r;
            const float* wrow = weff + (size_t)(ci * NTAP) * COUT + cg * 8;
            const float* xr   = &xsf[r][PADW + wl];
            #pragma unroll
            for (int t = 0; t < NTAP; ++t) {
                const float4 w0 = *reinterpret_cast<const float4*>(wrow + t * COUT);
                const float4 w1 = *reinterpret_cast<const float4*>(wrow + t * COUT + 4);
                float xvv[16];
                #pragma unroll
                for (int i = 0; i < 16; ++i) xvv[i] = xr[OFFS[t] + 32 * i];
                const float wv[8] = {w0.x, w0.y, w0.z, w0.w, w1.x, w1.y, w1.z, w1.w};
                #pragma unroll
                for (int j = 0; j < 8; ++j)
                    #pragma unroll
                    for (int i = 0; i < 16; ++i)
                        acc[j][i] = fmaf(wv[j], xvv[i], acc[j][i]);
            }
        }
    }
    float* outbase = out + (((size_t)b * COUT + cg * 8) * HH + h) * WW + wl;
    #pragma unroll
    for (int j = 0; j < 8; ++j)
        #pragma unroll
        for (int i = 0; i < 16; ++i) {
            float v = acc[j][i];
            outbase[(size_t)j * HW + 32 * i] = v > 0.f ? v : 0.f;
        }
}

// ---------------------------------------------------------------------------

extern "C" void kernel_launch(void* const* d_in, const int* in_sizes, int n_in,
                              void* d_out, int out_size, void* d_ws, size_t ws_size,
                              hipStream_t stream) {
    const float* x  = (const float*)d_in[0];
    const float* W  = (const float*)d_in[1];
    const float* Bv = (const float*)d_in[2];
    float* out = (float*)d_out;

    const size_t need = 139264 + 256;              // wf + bsum

    if (ws_size >= need) {
        __hip_bfloat16* wf = (__hip_bfloat16*)d_ws;               // 139,264 B
        float* bsum = (float*)((char*)d_ws + 139264);             // 256 B
        prep_wfrag<<<272, 256, 0, stream>>>(W, Bv, wf, bsum);
        (void)hipFuncSetAttribute((const void*)hdc_mfma,
            hipFuncAttributeMaxDynamicSharedMemorySize, 2 * BUFB);
        hdc_mfma<<<256, 256, 2 * BUFB, stream>>>(x, wf, bsum, out);
    } else {
        float* weff = (float*)d_ws;
        float* bsum = weff + (size_t)CIN * NTAP * COUT;
        prep_weff_fb<<<(CIN * NTAP * COUT + 255) / 256, 256, 0, stream>>>(W, Bv, weff, bsum);
        hdc_fb<<<NB * HH, 256, 0, stream>>>(x, weff, bsum, out);
    }
}

// Round 11
// 80.614 us; speedup vs baseline: 1.9964x; 1.0529x over previous
//
#include <hip/hip_runtime.h>
#include <hip/hip_bf16.h>
#include <stdint.h>

typedef float  f32x4 __attribute__((ext_vector_type(4)));
typedef short  s16x8 __attribute__((ext_vector_type(8)));

#define NB    8
#define CIN   64
#define COUT  64
#define HH    128
#define WW    512
#define NTAP  17
#define PADW  152
#define XROW  816            // PADW + WW + PADW
#define BUFB  (XROW * 64)    // 52,224 B per buffer
#define HW    (HH * WW)

// ---------------------------------------------------------------------------
// weights in A-fragment order: byte off = (2t+p)*4096 + m*1024 + lane*16
__global__ __launch_bounds__(256) void prep_wfrag(
        const float* __restrict__ W, const float* __restrict__ Bv,
        __hip_bfloat16* __restrict__ wf, float* __restrict__ bsum) {
    int idx = blockIdx.x * 256 + threadIdx.x;      // 69,632 total
    if (idx < NTAP * 2 * 4 * 64 * 8) {
        int j  = idx & 7;
        int l  = (idx >> 3) & 63;
        int m  = (idx >> 9) & 3;
        int pp = (idx >> 11) & 1;
        int t  = idx >> 12;
        int ci = pp * 32 + 8 * (l >> 4) + j;
        int co = 16 * m + (l & 15);
        float v;
        if (t == 0) {
            v = 0.f;
            #pragma unroll
            for (int i = 0; i < NB; ++i) v += W[((i * COUT + co) * CIN + ci) * 3 + 1];
        } else if (t <= 8) {
            v = W[(((t - 1) * COUT + co) * CIN + ci) * 3 + 0];
        } else {
            v = W[(((t - 9) * COUT + co) * CIN + ci) * 3 + 2];
        }
        wf[idx] = __float2bfloat16(v);
    }
    if (idx < COUT) {
        float s = 0.f;
        #pragma unroll
        for (int i = 0; i < NB; ++i) s += Bv[i * COUT + idx];
        bsum[idx] = s;
    }
}

static constexpr int OFFS[NTAP] = {0, -48, -76, -96, -111, -124, -135, -144, -152,
                                      48,  76,  96,  111,  124,  135,  144,  152};

#define SB __builtin_amdgcn_sched_barrier(0)

#define LOADAF(AF, T0, CNT)                                                    \
    _Pragma("unroll")                                                          \
    for (int i = 0; i < (CNT); ++i)                                            \
        _Pragma("unroll")                                                      \
        for (int mm = 0; mm < 2; ++mm)                                         \
            AF[i][mm] = *reinterpret_cast<const s16x8*>(                       \
                wbase + ((T0) + i) * 8192 + (2 * mg + mm) * 1024);

#define COMPTAPS(AF, T0, CNT)                                                  \
    _Pragma("unroll")                                                          \
    for (int i = 0; i < (CNT); ++i) {                                          \
        const int t      = (T0) + i;                                           \
        const int ldsrow = rowb + OFFS[t];                                     \
        const int slot   = lhi ^ ((ldsrow >> 1) & 3);                          \
        const char* bbase = rb + ldsrow * 64 + slot * 16;                      \
        s16x8 bfr[8];                                                          \
        _Pragma("unroll")                                                      \
        for (int n = 0; n < 8; ++n)                                            \
            bfr[n] = *reinterpret_cast<const s16x8*>(bbase + n * 1024);        \
        _Pragma("unroll")                                                      \
        for (int mm = 0; mm < 2; ++mm)                                         \
            _Pragma("unroll")                                                  \
            for (int n = 0; n < 8; ++n)                                        \
                acc[mm][n] = __builtin_amdgcn_mfma_f32_16x16x32_bf16(          \
                    AF[i][mm], bfr[n], acc[mm][n], 0, 0, 0);                   \
    }

// Fused persistent main: 256 blocks x 512 thr (8 waves @ 2/SIMD). Wave wv:
// mg = wv>>2 (m-pair -> 32 co), ws = wv&3 (128-w slice). acc[2][8]=64 VGPR,
// af batches 4-5 taps x 2m, xv staging 8 float4/thread -> peak ~190 VGPR so
// TWO waves/SIMD co-schedule (R10 lesson: 1 wave/SIMD exposes every latency).
// Per unit: compute on buf[u&1] (af-preloaded, vmem-free MFMA), SLOAD(u+1)
// issued as NEWEST vmem under last tap batch, vmcnt(0), SWRITE into other
// buffer, one s_barrier. x read once fp32, out written once: floor ~43us.
__global__ __launch_bounds__(512, 2) void hdc_mfma(
        const float* __restrict__ x, const __hip_bfloat16* __restrict__ wf,
        const float* __restrict__ bsum, float* __restrict__ out) {
    extern __shared__ __align__(16) char smem[];   // 2 * BUFB = 104,448 B

    const int tid  = threadIdx.x;
    const int wv   = tid >> 6;                     // wave 0..7
    const int lane = tid & 63;
    const int l15  = lane & 15;
    const int lhi  = lane >> 4;
    const int mg   = wv >> 2;                      // m-pair 0/1 (co 32-half)
    const int ws   = wv & 3;                       // w-slice 0..3
    const int c    = tid >> 7;                     // staging chunk 0..3
    const int wl   = tid & 127;                    // staging w/4 index
    const int bh0  = blockIdx.x * 4;               // 4 rows per block
    const int wlo  = ws * 128;
    const int rowb = PADW + wlo + l15;

    f32x4 acc[2][8];
    #pragma unroll
    for (int mm = 0; mm < 2; ++mm) {
        f32x4 bi = *reinterpret_cast<const f32x4*>(
            bsum + mg * 32 + 16 * mm + 4 * lhi);
        #pragma unroll
        for (int n = 0; n < 8; ++n) acc[mm][n] = bi;
    }

    // zero halos once in BOTH buffers (staging writes body rows only)
    {
        const int4 z{0, 0, 0, 0};
        #pragma unroll
        for (int bb = 0; bb < 2; ++bb) {
            int4* base = reinterpret_cast<int4*>(smem + bb * BUFB);
            for (int f = tid; f < 608; f += 512) {
                base[f] = z;                       // left halo  rows [0,152)
                base[2656 + f] = z;                // right halo rows [664,816)
            }
        }
    }

    float4 xv[8];                                  // staged fp32: 8 ci x 4 w

    auto SLOAD = [&](int u) {
        const int r = bh0 + (u >> 1);
        const int b = r >> 7, h = r & 127;
        const float* src = x +
            (((size_t)(b * CIN + (u & 1) * 32 + c * 8) * HH + h) * WW) + wl * 4;
        #pragma unroll
        for (int j = 0; j < 8; ++j)
            xv[j] = *reinterpret_cast<const float4*>(src + j * HW);
    };
    auto SWRITE = [&](int u) {
        char* dst = smem + (u & 1) * BUFB;
        #pragma unroll
        for (int k = 0; k < 4; ++k) {
            const int row  = PADW + wl * 4 + k;
            const int slot = c ^ ((row >> 1) & 3);
            union { __hip_bfloat16 hs[8]; int4 iv; } pk;
            #pragma unroll
            for (int j = 0; j < 8; ++j)
                pk.hs[j] = __float2bfloat16(((const float*)&xv[j])[k]);
            *reinterpret_cast<int4*>(dst + row * 64 + slot * 16) = pk.iv;
        }
    };

    // prologue: fill buf0
    SLOAD(0);
    asm volatile("s_waitcnt vmcnt(0)" ::: "memory");
    SB;
    SWRITE(0);
    __syncthreads();

    for (int u = 0; u < 8; ++u) {
        const char* wbase = (const char*)wf + (u & 1) * 4096 + lane * 16;
        const char* rb    = smem + (u & 1) * BUFB;

        s16x8 af0[4][2], af1[4][2], af2[4][2], af3[5][2];

        LOADAF(af0, 0, 4)  SB;
        COMPTAPS(af0, 0, 4) SB;
        LOADAF(af1, 4, 4)  SB;
        COMPTAPS(af1, 4, 4) SB;
        LOADAF(af2, 8, 4)  SB;
        COMPTAPS(af2, 8, 4) SB;
        LOADAF(af3, 12, 5) SB;
        if (u < 7) SLOAD(u + 1);                   // newest vmem: stays in flight
        SB;
        COMPTAPS(af3, 12, 5) SB;

        if (u & 1) {
            // row finished: ReLU + store, reinit acc with bias
            const int r = bh0 + (u >> 1);
            const int b = r >> 7, h = r & 127;
            float* obase = out +
                (((size_t)b * COUT + mg * 32 + 4 * lhi) * HH + h) * WW + wlo + l15;
            #pragma unroll
            for (int mm = 0; mm < 2; ++mm)
                #pragma unroll
                for (int n = 0; n < 8; ++n)
                    #pragma unroll
                    for (int rr = 0; rr < 4; ++rr) {
                        float v = acc[mm][n][rr];
                        obase[(size_t)(16 * mm + rr) * HW + 16 * n] =
                            v > 0.f ? v : 0.f;
                    }
            #pragma unroll
            for (int mm = 0; mm < 2; ++mm) {
                f32x4 bi = *reinterpret_cast<const f32x4*>(
                    bsum + mg * 32 + 16 * mm + 4 * lhi);
                #pragma unroll
                for (int n = 0; n < 8; ++n) acc[mm][n] = bi;
            }
        }

        if (u < 7) {
            asm volatile("s_waitcnt vmcnt(0)" ::: "memory");   // xv landed
            SB;
            SWRITE(u + 1);                         // into buf[(u+1)&1]
        }

        asm volatile("s_waitcnt lgkmcnt(0)" ::: "memory");     // ds_writes done
        SB;
        __builtin_amdgcn_s_barrier();              // buf ready for all waves
    }
}

// ---------------------------------------------------------------------------
// FALLBACK (round-1 fp32 kernel) if ws_size is too small for weight scratch
// ---------------------------------------------------------------------------
#define CI_STAGE 16

__global__ void prep_weff_fb(const float* __restrict__ W, const float* __restrict__ Bv,
                             float* __restrict__ weff, float* __restrict__ bsum) {
    int idx = blockIdx.x * 256 + threadIdx.x;
    if (idx < CIN * NTAP * COUT) {
        int co = idx & 63;
        int t  = (idx >> 6) % NTAP;
        int ci = idx / (NTAP * COUT);
        float v;
        if (t == 0) {
            v = 0.f;
            #pragma unroll
            for (int i = 0; i < NB; ++i) v += W[(((i * COUT + co) * CIN + ci) * 3) + 1];
        } else if (t <= 8) {
            v = W[((((t - 1) * COUT + co) * CIN + ci) * 3) + 0];
        } else {
            v = W[((((t - 9) * COUT + co) * CIN + ci) * 3) + 2];
        }
        weff[(ci * NTAP + t) * COUT + co] = v;
    }
    if (idx < COUT) {
        float s = 0.f;
        #pragma unroll
        for (int i = 0; i < NB; ++i) s += Bv[i * COUT + idx];
        bsum[idx] = s;
    }
}

__global__ __launch_bounds__(256, 2) void hdc_fb(
        const float* __restrict__ x, const float* __restrict__ weff,
        const float* __restrict__ bsum, float* __restrict__ out) {
    __shared__ float xsf[CI_STAGE][XROW];
    const int bh  = blockIdx.x;
    const int b   = bh >> 7;
    const int h   = bh & (HH - 1);
    const int tid = threadIdx.x;
    const int cg  = tid >> 5;
    const int wl  = tid & 31;
    float acc[8][16];
    #pragma unroll
    for (int j = 0; j < 8; ++j) {
        const float bj = bsum[cg * 8 + j];
        #pragma unroll
        for (int i = 0; i < 16; ++i) acc[j][i] = bj;
    }
    const float* xrowbase = x + ((size_t)(b * CIN) * HH + h) * WW;
    for (int s = 0; s < CIN / CI_STAGE; ++s) {
        __syncthreads();
        for (int f = tid; f < CI_STAGE * PADW; f += 256) {
            int r = f / PADW, cc = f - r * PADW;
            xsf[r][cc] = 0.f;
            xsf[r][PADW + WW + cc] = 0.f;
        }
        #pragma unroll
        for (int j = 0; j < 8; ++j) {
            int flat = j * 256 + tid;
            int r = flat >> 7, c4 = flat & 127;
            const float4 v = *reinterpret_cast<const float4*>(
                xrowbase + (size_t)(s * CI_STAGE + r) * HW + c4 * 4);
            *reinterpret_cast<float4*>(&xsf[r][PADW + c4 * 4]) = v;
        }
        __syncthreads();
        for (int r = 0; r < CI_STAGE; ++r) {
            const int ci = s * CI_STAGE + r;
            const float* wrow = weff + (size_t)(ci * NTAP) * COUT + cg * 8;
            const float* xr   = &xsf[r][PADW + wl];
            #pragma unroll
            for (int t = 0; t < NTAP; ++t) {
                const float4 w0 = *reinterpret_cast<const float4*>(wrow + t * COUT);
                const float4 w1 = *reinterpret_cast<const float4*>(wrow + t * COUT + 4);
                float xvv[16];
                #pragma unroll
                for (int i = 0; i < 16; ++i) xvv[i] = xr[OFFS[t] + 32 * i];
                const float wv2[8] = {w0.x, w0.y, w0.z, w0.w, w1.x, w1.y, w1.z, w1.w};
                #pragma unroll
                for (int j = 0; j < 8; ++j)
                    #pragma unroll
                    for (int i = 0; i < 16; ++i)
                        acc[j][i] = fmaf(wv2[j], xvv[i], acc[j][i]);
            }
        }
    }
    float* outbase = out + (((size_t)b * COUT + cg * 8) * HH + h) * WW + wl;
    #pragma unroll
    for (int j = 0; j < 8; ++j)
        #pragma unroll
        for (int i = 0; i < 16; ++i) {
            float v = acc[j][i];
            outbase[(size_t)j * HW + 32 * i] = v > 0.f ? v : 0.f;
        }
}

// ---------------------------------------------------------------------------

extern "C" void kernel_launch(void* const* d_in, const int* in_sizes, int n_in,
                              void* d_out, int out_size, void* d_ws, size_t ws_size,
                              hipStream_t stream) {
    const float* x  = (const float*)d_in[0];
    const float* W  = (const float*)d_in[1];
    const float* Bv = (const float*)d_in[2];
    float* out = (float*)d_out;

    const size_t need = 139264 + 256;              // wf + bsum

    if (ws_size >= need) {
        __hip_bfloat16* wf = (__hip_bfloat16*)d_ws;               // 139,264 B
        float* bsum = (float*)((char*)d_ws + 139264);             // 256 B
        prep_wfrag<<<272, 256, 0, stream>>>(W, Bv, wf, bsum);
        (void)hipFuncSetAttribute((const void*)hdc_mfma,
            hipFuncAttributeMaxDynamicSharedMemorySize, 2 * BUFB);
        hdc_mfma<<<256, 512, 2 * BUFB, stream>>>(x, wf, bsum, out);
    } else {
        float* weff = (float*)d_ws;
        float* bsum = weff + (size_t)CIN * NTAP * COUT;
        prep_weff_fb<<<(CIN * NTAP * COUT + 255) / 256, 256, 0, stream>>>(W, Bv, weff, bsum);
        hdc_fb<<<NB * HH, 256, 0, stream>>>(x, weff, bsum, out);
    }
}